// Round 5
// baseline (531.981 us; speedup 1.0000x reference)
//
#include <hip/hip_runtime.h>
#include <math.h>

#define K_EMB 1024
#define D_DIM 256
#define T_SZ 2048
#define TOT 16777216        // B*D*T
#define LOSS_OFF 16777216
#define IDX_OFF 16777217
#define NDC 17              // 16 real d-chunks + 1 esq-fold chunk (A-side)
#define THR 0.6f            // ~10 sigma of bf16 score noise -> exact refine

// kernel A dynamic LDS layout (bytes); q overlay [0,65792) after main loop
#define SM_XH   0           // 32,768  x frags: [tc2][dc16][64 lane][16B]
#define SM_X2P  32768       //  2,048  per-thread x^2 partials (512 f32)
#define SM_REDV 34816       //  6,144  top3 vals [8w][2tcj][32m][3]
#define SM_REDK 40960       //  6,144  top3 keys
#define SM_IDX  65792       //    256  (above q overlay: live through gather)
#define SM_TIEC 66048       //      8  tie count
#define SM_TIEL 66056       //    512  64 x uint2 tie entries
#define SM_TOT  66568

typedef __attribute__((ext_vector_type(8)))  __bf16 bf16x8;
typedef __attribute__((ext_vector_type(8)))  short  s16x8;
typedef __attribute__((ext_vector_type(16))) float  f32x16;

__device__ __forceinline__ unsigned short f2bf(float f) {   // RNE fp32->bf16 bits
    unsigned u = __float_as_uint(f);
    u += 0x7FFFu + ((u >> 16) & 1u);
    return (unsigned short)(u >> 16);
}
__device__ __forceinline__ float bf2f(unsigned short h) {
    return __uint_as_float(((unsigned)h) << 16);
}
// top-3 insert, maximizing, tie -> smaller k. Insertion-order-safe.
__device__ __forceinline__ void ins3(float& v1, int& k1, float& v2, int& k2,
                                     float& v3, int& k3, float v, int k) {
    bool b1 = (v > v1) || (v == v1 && k < k1);
    bool b2 = (v > v2) || (v == v2 && k < k2);
    bool b3 = (v > v3) || (v == v3 && k < k3);
    if (b1)      { v3 = v2; k3 = k2; v2 = v1; k2 = k1; v1 = v; k1 = k; }
    else if (b2) { v3 = v2; k3 = k2; v2 = v;  k2 = k; }
    else if (b3) { v3 = v;  k3 = k; }
}

// --- Kernel 0: pre-pack E into MFMA A-frag order (bf16, hi only) ----------
// frag (kc, dc, lane): A[m=lane&31][kd=(lane>>5)*8+j], k=kc*32+m,
// d=dc*16+(lane>>5)*8+j. dc==16 = esq-fold: slot0=bf16(-esq/2), slot1=residual
// (both hit B=1.0 -> 2-term esq to ~2^-16). Also zeroes loss accumulator.
__global__ __launch_bounds__(256) void prepack_kernel(const float* __restrict__ E,
        unsigned short* __restrict__ Ehi, float* __restrict__ loss) {
    if (blockIdx.x == 0 && threadIdx.x == 0) loss[0] = 0.f;
    int gid = blockIdx.x * 256 + threadIdx.x;        // == (kc*17+dc)*64 + lane
    if (gid >= 32 * NDC * 64) return;
    int lane = gid & 63;
    int dc = (gid >> 6) % NDC;
    int kc = gid / (NDC * 64);
    int m = lane & 31, dh = lane >> 5;
    int k = kc * 32 + m;
    unsigned short h8[8];
#pragma unroll
    for (int j = 0; j < 8; ++j) h8[j] = 0;
    if (dc < 16) {
        int d0 = dc * 16 + dh * 8;
        const float* ep = E + (size_t)k * D_DIM + d0;
#pragma unroll
        for (int j = 0; j < 8; ++j) h8[j] = f2bf(ep[j]);
    } else if (dh == 0) {
        const float* er = E + (size_t)k * D_DIM;
        float s0 = 0.f, s1 = 0.f, s2 = 0.f, s3 = 0.f;
        for (int i = 0; i < D_DIM; i += 4) {
            s0 = fmaf(er[i], er[i], s0);
            s1 = fmaf(er[i + 1], er[i + 1], s1);
            s2 = fmaf(er[i + 2], er[i + 2], s2);
            s3 = fmaf(er[i + 3], er[i + 3], s3);
        }
        float v = -0.5f * ((s0 + s1) + (s2 + s3));
        unsigned short h = f2bf(v);
        h8[0] = h;
        h8[1] = f2bf(v - bf2f(h));
    }
    s16x8 hv;
#pragma unroll
    for (int j = 0; j < 8; ++j) hv[j] = (short)h8[j];
    ((s16x8*)Ehi)[gid] = hv;
}

// --- Kernel A: argmin (plain bf16 MFMA, top-3 guard) + loss + gather + out -
// 512 thr / 8 waves, t-tile 64 (2 tcj), grid 1024, 2 blocks/CU (67KB LDS).
// Wave w owns kc pair {kcg*16+2w, +1} per kcg round: acc[2][2] f32x16 = 64
// AGPRs; ~110 total regs -> 4 waves/SIMD. NO barriers in main loop; E frags
// via rotating depth-1 prefetch from L2. Near-ties (gap<THR) -> exact fp64
// over top-3 candidates, wave-parallel.
__global__ __launch_bounds__(512, 4) void vq_fused_kernel(
        const float* __restrict__ X, const unsigned short* __restrict__ Ehi,
        const float* __restrict__ E, float* __restrict__ out0,
        float* __restrict__ loss, float* __restrict__ idxf_out) {
    extern __shared__ char smem[];
    unsigned short* xhf = (unsigned short*)(smem + SM_XH);
    float* x2p = (float*)(smem + SM_X2P);
    float* redv = (float*)(smem + SM_REDV);
    int*   redk = (int*)(smem + SM_REDK);
    int*   idxs = (int*)(smem + SM_IDX);
    int*   tiec = (int*)(smem + SM_TIEC);
    uint2* tiel = (uint2*)(smem + SM_TIEL);
    float* q    = (float*)smem;              // overlay [64][257] after main

    int tid = threadIdx.x;
    int lane = tid & 63;
    int w = tid >> 6;                        // 0..7
    int b = blockIdx.x >> 5;                 // 32 tiles of 64 t per b
    int tg0 = (blockIdx.x & 31) << 6;

    if (tid == 0) tiec[0] = 0;

    // ---- stage X tile [64 t][256 d] -> frag-order bf16 in LDS ----
    {
        int t = tid & 63, dblk = tid >> 6;   // 8 dblk x 32 d
        int tc = t >> 5, m = t & 31;
        const float* xp = X + (size_t)b * ((size_t)D_DIM * T_SZ) + tg0 + t;
        float x2a = 0.f;
        for (int g = 0; g < 4; ++g) {
            int d0 = dblk * 32 + g * 8;
            s16x8 hv;
#pragma unroll
            for (int j = 0; j < 8; ++j) {
                float xv = xp[(size_t)(d0 + j) * T_SZ];
                hv[j] = (short)f2bf(xv);
                x2a = fmaf(xv, xv, x2a);
            }
            int dc = d0 >> 4, h = (d0 >> 3) & 1;
            int fi = (tc * 16 + dc) * 64 + h * 32 + m;
            ((s16x8*)xhf)[fi] = hv;
        }
        x2p[tid] = x2a;
    }
    __syncthreads();

    int dhalf = lane >> 5;
    const s16x8* ehp = (const s16x8*)Ehi;
    const s16x8* bhf = (const s16x8*)xhf;

    s16x8 bfold = {0, 0, 0, 0, 0, 0, 0, 0};
    if (dhalf == 0) { bfold[0] = (short)0x3F80; bfold[1] = (short)0x3F80; }
    bf16x8 bh_fold = __builtin_bit_cast(bf16x8, bfold);

    float v1s[2], v2s[2], v3s[2];
    int k1s[2], k2s[2], k3s[2];
#pragma unroll
    for (int j = 0; j < 2; ++j) { v1s[j] = -INFINITY; v2s[j] = -INFINITY;
                                  v3s[j] = -INFINITY; k1s[j] = 0; k2s[j] = 0;
                                  k3s[j] = 0; }

#pragma unroll 1
    for (int kcg = 0; kcg < 2; ++kcg) {
        int kcb = kcg * 16 + w * 2;          // owns kcb, kcb+1
        f32x16 acc[2][2];
#pragma unroll
        for (int kci = 0; kci < 2; ++kci)
#pragma unroll
            for (int tcj = 0; tcj < 2; ++tcj)
#pragma unroll
                for (int i = 0; i < 16; ++i) acc[kci][tcj][i] = 0.f;

        // rotating depth-1 prefetch of E frags (L2-resident)
        size_t ab = ((size_t)kcb * NDC) * 64 + lane;
        s16x8 nh0 = ehp[ab];
        s16x8 nh1 = ehp[ab + NDC * 64];

#pragma unroll 1
        for (int dc = 0; dc < 16; ++dc) {
            bf16x8 ah0 = __builtin_bit_cast(bf16x8, nh0);
            bf16x8 ah1 = __builtin_bit_cast(bf16x8, nh1);
            size_t an = ab + (size_t)(dc + 1) * 64;   // dc==15 -> fold chunk
            nh0 = ehp[an];
            nh1 = ehp[an + NDC * 64];
            bf16x8 bh0 = __builtin_bit_cast(bf16x8, bhf[dc * 64 + lane]);
            bf16x8 bh1 = __builtin_bit_cast(bf16x8, bhf[(16 + dc) * 64 + lane]);
            acc[0][0] = __builtin_amdgcn_mfma_f32_32x32x16_bf16(ah0, bh0, acc[0][0], 0, 0, 0);
            acc[0][1] = __builtin_amdgcn_mfma_f32_32x32x16_bf16(ah0, bh1, acc[0][1], 0, 0, 0);
            acc[1][0] = __builtin_amdgcn_mfma_f32_32x32x16_bf16(ah1, bh0, acc[1][0], 0, 0, 0);
            acc[1][1] = __builtin_amdgcn_mfma_f32_32x32x16_bf16(ah1, bh1, acc[1][1], 0, 0, 0);
        }
        {   // esq-fold chunk (prefetched): B constant 1.0 in kd slots 0,1
            bf16x8 ah0 = __builtin_bit_cast(bf16x8, nh0);
            bf16x8 ah1 = __builtin_bit_cast(bf16x8, nh1);
#pragma unroll
            for (int tcj = 0; tcj < 2; ++tcj) {
                acc[0][tcj] = __builtin_amdgcn_mfma_f32_32x32x16_bf16(ah0, bh_fold, acc[0][tcj], 0, 0, 0);
                acc[1][tcj] = __builtin_amdgcn_mfma_f32_32x32x16_bf16(ah1, bh_fold, acc[1][tcj], 0, 0, 0);
            }
        }
        // scan acc -> per-tcj running top3 (insertion-order-safe)
#pragma unroll
        for (int kci = 0; kci < 2; ++kci) {
            int kb = (kcb + kci) * 32 + 4 * dhalf;
#pragma unroll
            for (int tcj = 0; tcj < 2; ++tcj)
#pragma unroll
                for (int r = 0; r < 16; ++r) {
                    int kk = kb + (r & 3) + 8 * (r >> 2);
                    ins3(v1s[tcj], k1s[tcj], v2s[tcj], k2s[tcj],
                         v3s[tcj], k3s[tcj], acc[kci][tcj][r], kk);
                }
        }
    }

    // merge lane^32 partner (same t, complementary k rows), store to LDS
#pragma unroll
    for (int tcj = 0; tcj < 2; ++tcj) {
        float pv1 = __shfl_xor(v1s[tcj], 32, 64); int pk1 = __shfl_xor(k1s[tcj], 32, 64);
        float pv2 = __shfl_xor(v2s[tcj], 32, 64); int pk2 = __shfl_xor(k2s[tcj], 32, 64);
        float pv3 = __shfl_xor(v3s[tcj], 32, 64); int pk3 = __shfl_xor(k3s[tcj], 32, 64);
        ins3(v1s[tcj], k1s[tcj], v2s[tcj], k2s[tcj], v3s[tcj], k3s[tcj], pv1, pk1);
        ins3(v1s[tcj], k1s[tcj], v2s[tcj], k2s[tcj], v3s[tcj], k3s[tcj], pv2, pk2);
        ins3(v1s[tcj], k1s[tcj], v2s[tcj], k2s[tcj], v3s[tcj], k3s[tcj], pv3, pk3);
        if (dhalf == 0) {
            int base = ((w * 2 + tcj) * 32 + (lane & 31)) * 3;
            redv[base]     = v1s[tcj]; redk[base]     = k1s[tcj];
            redv[base + 1] = v2s[tcj]; redk[base + 1] = k2s[tcj];
            redv[base + 2] = v3s[tcj]; redk[base + 2] = k3s[tcj];
        }
    }
    __syncthreads();

    // per-t reduce across 8 waves; near-ties -> deferred top-3 exact refine
    if (tid < 64) {
        int t = tid, tcj = t >> 5, m = t & 31;
        float v1 = -INFINITY, v2 = -INFINITY, v3 = -INFINITY;
        int k1 = 0, k2 = 0, k3 = 0;
#pragma unroll
        for (int ww = 0; ww < 8; ++ww) {
            int base = ((ww * 2 + tcj) * 32 + m) * 3;
            ins3(v1, k1, v2, k2, v3, k3, redv[base], redk[base]);
            ins3(v1, k1, v2, k2, v3, k3, redv[base + 1], redk[base + 1]);
            ins3(v1, k1, v2, k2, v3, k3, redv[base + 2], redk[base + 2]);
        }
        float dmin2 = 0.f;
        if (v1 - v2 < THR) {      // near-tie: defer exact fp64 refinement
            int slot = atomicAdd(tiec, 1);
            tiel[slot] = make_uint2(((unsigned)t << 10) | (unsigned)k1,
                                    ((unsigned)k2 << 16) | (unsigned)k3);
        } else {
            idxs[t] = k1;
            idxf_out[(size_t)b * T_SZ + tg0 + t] = (float)k1;
            float x2 = 0.f;
#pragma unroll
            for (int i = 0; i < 8; ++i) x2 += x2p[t + 64 * i];
            dmin2 = x2 - 2.0f * v1;   // ||x||^2 - 2(x.e - esq/2) = ||x-e||^2
        }
        float lsum = dmin2;
#pragma unroll
        for (int off = 32; off > 0; off >>= 1) lsum += __shfl_down(lsum, off, 64);
        if (tid == 0) atomicAdd(loss, lsum * (0.5f / (float)TOT));
    }
    __syncthreads();

    // wave-parallel exact refinement: one wave per tie, 64 lanes x 4 d each
    {
        int ntie = tiec[0];
        for (int e = w; e < ntie; e += 8) {
            uint2 pk = tiel[e];
            int t = pk.x >> 10;
            int k1 = pk.x & 1023, k2 = pk.y >> 16, k3 = pk.y & 1023;
            const float* e1 = E + (size_t)k1 * D_DIM;
            const float* e2 = E + (size_t)k2 * D_DIM;
            const float* e3 = E + (size_t)k3 * D_DIM;
            const float* xc = X + (size_t)b * ((size_t)D_DIM * T_SZ) + tg0 + t;
            int d0 = lane * 4;
            double d1 = 0.0, d2 = 0.0, d3 = 0.0;
#pragma unroll
            for (int u = 0; u < 4; ++u) {
                int d = d0 + u;
                double xd = (double)xc[(size_t)d * T_SZ];
                double u1 = xd - (double)e1[d];
                double u2 = xd - (double)e2[d];
                double u3 = xd - (double)e3[d];
                d1 += u1 * u1;
                d2 += u2 * u2;
                d3 += u3 * u3;
            }
#pragma unroll
            for (int off = 32; off > 0; off >>= 1) {
                d1 += __shfl_down(d1, off, 64);
                d2 += __shfl_down(d2, off, 64);
                d3 += __shfl_down(d3, off, 64);
            }
            if (lane == 0) {
                int kb = k1; double dm = d1;
                if (d2 < dm || (d2 == dm && k2 < kb)) { kb = k2; dm = d2; }
                if (d3 < dm || (d3 == dm && k3 < kb)) { kb = k3; dm = d3; }
                idxs[t] = kb;
                idxf_out[(size_t)b * T_SZ + tg0 + t] = (float)kb;
                atomicAdd(loss, (float)dm * (0.5f / (float)TOT));
            }
        }
    }
    __syncthreads();

    // gather E rows into q overlay (stride 257 -> conflict-free column reads)
    {
        for (int i = 0; i < 8; ++i) {
            int r = w * 8 + i;
            int row = idxs[r];
            const float* ep = E + (size_t)row * D_DIM;
#pragma unroll
            for (int u = 0; u < 4; ++u)
                q[r * 257 + lane + 64 * u] = ep[lane + 64 * u];
        }
    }
    __syncthreads();

    // write out0 [B,D,T]: lanes over t (coalesced), LDS reads conflict-free
    {
        int t = tid & 63, dgrp = tid >> 6;
        size_t obase = (size_t)b * ((size_t)D_DIM * T_SZ) + tg0 + t;
#pragma unroll 8
        for (int j = 0; j < 32; ++j) {
            int d = dgrp * 32 + j;
            out0[obase + (size_t)d * T_SZ] = q[t * 257 + d];
        }
    }
}

extern "C" void kernel_launch(void* const* d_in, const int* in_sizes, int n_in,
                              void* d_out, int out_size, void* d_ws, size_t ws_size,
                              hipStream_t stream) {
    const float* X = (const float*)d_in[0];   // [32, 256, 2048] fp32
    const float* E = (const float*)d_in[1];   // [1024, 256] fp32
    float* out = (float*)d_out;
    float* loss = out + LOSS_OFF;
    float* idxf = out + IDX_OFF;

    unsigned short* Ehi = (unsigned short*)d_ws;   // 544 KB packed frags

    prepack_kernel<<<(32 * NDC * 64 + 255) / 256, 256, 0, stream>>>(E, Ehi, loss);
    vq_fused_kernel<<<1024, 512, SM_TOT, stream>>>(X, Ehi, E, out, loss, idxf);
}